// Round 4
// baseline (483.014 us; speedup 1.0000x reference)
//
#include <hip/hip_runtime.h>
#include <hip/hip_bf16.h>
#include <stdint.h>

// CompressedLinear: out[M][N] = x[M][K] @ (w_int8[N][K] * scale[N])^T + bias[N]
// M=8192, K=4096, N=11008.
// R4: i8 GEMM, 32x32x32 MFMA, single barrier per K-tile, LDS reads software-
// pipelined under MFMA (2-state slice double-buffer), plain LDS double-buffer,
// pre-tiled/pre-swizzled operands in d_ws, 2D-grouped XCD-aware block order.

#define MT 8192
#define KT 4096
#define NT 11008
#define NKT 32             // K tiles of 128 (i8)
#define MTILES 32          // 8192/256
#define NTILES 43          // 11008/256
#define CHUNK_BYTES 32768  // 256 rows x 128 k x 1B

typedef __attribute__((ext_vector_type(8))) short short8;
typedef __attribute__((ext_vector_type(4))) float f32x4;
typedef __attribute__((ext_vector_type(4))) int i32x4;
typedef __attribute__((ext_vector_type(16))) int i32x16;
typedef __attribute__((ext_vector_type(16))) char char16;

static __device__ __forceinline__ short f2bf(float f) {
  union { float f; unsigned u; } c; c.f = f;
  unsigned u = c.u;
  return (short)((u + 0x7fffu + ((u >> 16) & 1u)) >> 16);  // RNE
}

// ---------------- x: per-row absmax quantize -> pre-tiled/swizzled i8 ----------------
// chunk byte(row, granule g=k/16) = row*128 + ((g*16) ^ ((row&7)<<4))
__global__ __launch_bounds__(256) void quant_x_kernel(const float* __restrict__ in,
                                                      char* __restrict__ Aws,
                                                      float* __restrict__ sx) {
  const int m = blockIdx.x;
  const int t = threadIdx.x;
  const float* row = in + (size_t)m * KT + t * 16;
  f32x4 v[4];
  float mx = 0.f;
#pragma unroll
  for (int i = 0; i < 4; i++) {
    v[i] = *(const f32x4*)(row + i * 4);
#pragma unroll
    for (int j = 0; j < 4; j++) mx = fmaxf(mx, fabsf(v[i][j]));
  }
#pragma unroll
  for (int off = 32; off; off >>= 1) mx = fmaxf(mx, __shfl_xor(mx, off));
  __shared__ float smx[4];
  if ((t & 63) == 0) smx[t >> 6] = mx;
  __syncthreads();
  mx = fmaxf(fmaxf(smx[0], smx[1]), fmaxf(smx[2], smx[3]));
  const float inv = 127.0f / mx;
  if (t == 0) sx[m] = mx * (1.0f / 127.0f);
  char16 q;
#pragma unroll
  for (int i = 0; i < 4; i++)
#pragma unroll
    for (int j = 0; j < 4; j++) q[i * 4 + j] = (char)(int)rintf(v[i][j] * inv);
  const int mt = m >> 8, r = m & 255, kt = t >> 3, g = t & 7;
  *(char16*)(Aws + ((size_t)mt * NKT + kt) * CHUNK_BYTES + r * 128 +
             ((g * 16) ^ ((r & 7) << 4))) = q;
}

// ---------------- w: int32 codes -> pre-tiled/swizzled i8 (exact) ----------------
__global__ __launch_bounds__(256) void cvt_w8_kernel(const int* __restrict__ in,
                                                     char* __restrict__ Bws) {
  const int n = blockIdx.x;
  const int t = threadIdx.x;
  const int* s = in + (size_t)n * KT + t * 16;
  char16 q;
#pragma unroll
  for (int i = 0; i < 4; i++) {
    i32x4 a = *(const i32x4*)(s + i * 4);
#pragma unroll
    for (int j = 0; j < 4; j++) q[i * 4 + j] = (char)a[j];
  }
  const int nt = n >> 8, r = n & 255, kt = t >> 3, g = t & 7;
  *(char16*)(Bws + ((size_t)nt * NKT + kt) * CHUNK_BYTES + r * 128 +
             ((g * 16) ^ ((r & 7) << 4))) = q;
}

// ---------------- 256x256 i8 GEMM, 32x32x32 MFMA, 1 barrier/K-tile ----------------
// LDS: buf c at c*65536: A (32KB) then B (32KB); plain double buffer = 128KB.
// 8 waves: wr=wid>>2, wc=wid&3; per-wave output 128x64 = 4x2 frags of 32x32.
// K-tile 128 = 4 slices of 32. Per slice: 4 A-frags + 2 B-frags (6 ds_read_b128),
// 8 MFMA. Slices 2-state double-buffered in regs; reads of s+1 overlap MFMA of s.
// Boundary: lgkmcnt0 (all reads of buf c consumed) + vmcnt0 (t+1 landed, issued a
// full tile ago -> free) + s_barrier; then head-read slice0 of t+1 from buf c^1
// and issue GLD t+2 into buf c.

#define GLD(chunk, j, ldsbase)                                                   \
  __builtin_amdgcn_global_load_lds(                                              \
      (const __attribute__((address_space(1))) void*)((chunk) + (j) * 8192 +     \
                                                      tid * 16),                 \
      (__attribute__((address_space(3))) void*)((ldsbase) + (j) * 8192 +         \
                                                wid * 1024),                     \
      16, 0, 0)

#define BAR asm volatile("s_barrier" ::: "memory")
#define VMC0 asm volatile("s_waitcnt vmcnt(0)" ::: "memory")
#define LGK0 asm volatile("s_waitcnt lgkmcnt(0)" ::: "memory")

// A-frag (32x32x32 i8): lane l -> row = l&31 (+32*mb), k-bytes (l>>5)*16..+15.
// B-frag: lane l -> col(row of w) = l&31 (+32*nb), same k split.
#define KOFF(s) ((((s) * 32) + khalf) ^ swz)

#define LDSL(LAp, s, aset, bset)                                \
  do {                                                          \
    const int ko_ = KOFF(s);                                    \
    aset[0] = *(const i32x4*)((LAp) + aoff + ko_);              \
    aset[1] = *(const i32x4*)((LAp) + aoff + 4096 + ko_);       \
    aset[2] = *(const i32x4*)((LAp) + aoff + 8192 + ko_);       \
    aset[3] = *(const i32x4*)((LAp) + aoff + 12288 + ko_);      \
    bset[0] = *(const i32x4*)((LAp) + boff + ko_);              \
    bset[1] = *(const i32x4*)((LAp) + boff + 4096 + ko_);       \
  } while (0)

#define MMS(aset, bset)                                                        \
  do {                                                                         \
    __builtin_amdgcn_s_setprio(1);                                             \
    _Pragma("unroll") for (int mb = 0; mb < 4; mb++)                           \
        _Pragma("unroll") for (int nb = 0; nb < 2; nb++)                       \
            acc[mb][nb] = __builtin_amdgcn_mfma_i32_32x32x32_i8(               \
                aset[mb], bset[nb], acc[mb][nb], 0, 0, 0);                     \
    __builtin_amdgcn_s_setprio(0);                                             \
  } while (0)

__global__ __launch_bounds__(512, 2) void gemm256(
    const char* __restrict__ Aws, const char* __restrict__ Bws,
    const float* __restrict__ sx, const float* __restrict__ scale,
    const float* __restrict__ bias, float* __restrict__ out) {
  extern __shared__ char Lsm[];
  const int tid = threadIdx.x;
  const int lane = tid & 63;
  const int wid = tid >> 6;
  const int wr = wid >> 2;
  const int wc = wid & 3;

  // XCD chunking + 2D grouped ordering (R3-proven: FETCH 1.5GB -> 324MB)
  const int bid = blockIdx.x;
  const int lid = (bid & 7) * 172 + (bid >> 3);  // nwg=1376, /8=172
  const int g8 = lid / 344;
  const int r8 = lid - g8 * 344;
  const int mt = g8 * 8 + (r8 & 7);
  const int nt = r8 >> 3;

  const char* Ach = Aws + (size_t)mt * NKT * CHUNK_BYTES;
  const char* Bch = Bws + (size_t)nt * NKT * CHUNK_BYTES;

  const int aoff = (wr * 128 + (lane & 31)) * 128;          // A region byte base
  const int boff = 32768 + (wc * 64 + (lane & 31)) * 128;   // B region byte base
  const int khalf = (lane >> 5) * 16;
  const int swz = (lane & 7) << 4;

  i32x16 acc[4][2] = {};
  i32x4 a0[4], a1[4], b0[2], b1[2];

  // ---- prologue: tile0 -> buf0; wait+bar; issue tile1 -> buf1; head slice0 ----
  {
    char* lA0 = Lsm;
    char* lB0 = Lsm + 32768;
    GLD(Bch, 0, lB0); GLD(Bch, 1, lB0); GLD(Bch, 2, lB0); GLD(Bch, 3, lB0);
    GLD(Ach, 0, lA0); GLD(Ach, 1, lA0); GLD(Ach, 2, lA0); GLD(Ach, 3, lA0);
    VMC0;
    BAR;
    const char* A1 = Ach + CHUNK_BYTES;
    const char* B1 = Bch + CHUNK_BYTES;
    char* lA1 = Lsm + 65536;
    char* lB1 = Lsm + 65536 + 32768;
    GLD(B1, 0, lB1); GLD(B1, 1, lB1); GLD(B1, 2, lB1); GLD(B1, 3, lB1);
    GLD(A1, 0, lA1); GLD(A1, 1, lA1); GLD(A1, 2, lA1); GLD(A1, 3, lA1);
    LDSL(Lsm, 0, a0, b0);
  }

  for (int t = 0; t < NKT; ++t) {
    const char* LA = Lsm + (t & 1) * 65536;

    LDSL(LA, 1, a1, b1);  MMS(a0, b0);   // slice0 compute || slice1 reads
    LDSL(LA, 2, a0, b0);  MMS(a1, b1);
    LDSL(LA, 3, a1, b1);  MMS(a0, b0);
    MMS(a1, b1);                         // slice3

    LGK0;   // all our reads of buf c consumed (cheap: already waited by MFMAs)
    VMC0;   // tile t+1's 8 loads landed (issued a full tile ago)
    BAR;    // all waves: done reading buf c, t+1 fully in buf c^1

    if (t + 1 < NKT) {
      const char* LAn = Lsm + ((t + 1) & 1) * 65536;
      if (t + 2 < NKT) {  // stage t+2 into buf c (just freed)
        char* dA = Lsm + (t & 1) * 65536;
        char* dB = dA + 32768;
        const char* A2 = Ach + 2 * CHUNK_BYTES;
        const char* B2 = Bch + 2 * CHUNK_BYTES;
        GLD(B2, 0, dB); GLD(B2, 1, dB); GLD(B2, 2, dB); GLD(B2, 3, dB);
        GLD(A2, 0, dA); GLD(A2, 1, dA); GLD(A2, 2, dA); GLD(A2, 3, dA);
      }
      LDSL(LAn, 0, a0, b0);  // head: slice0 of tile t+1
    }
    Ach += CHUNK_BYTES;
    Bch += CHUNK_BYTES;
  }

  // ---- epilogue: 32x32 C/D layout (m74/m101): col=lane&31,
  //      row=(reg&3)+8*(reg>>2)+4*(lane>>5) ----
  const int col0 = nt * 256 + wc * 64 + (lane & 31);
  const int row0 = mt * 256 + wr * 128 + ((lane >> 5) << 2);
#pragma unroll
  for (int mb = 0; mb < 4; mb++) {
    f32x4 sxq[4];
#pragma unroll
    for (int g = 0; g < 4; g++)
      sxq[g] = *(const f32x4*)(sx + row0 + mb * 32 + g * 8);
#pragma unroll
    for (int nb = 0; nb < 2; nb++) {
      const int n = col0 + nb * 32;
      const float sc = scale[n];
      const float bs = bias[n];
#pragma unroll
      for (int g = 0; g < 4; g++)
#pragma unroll
        for (int j = 0; j < 4; j++) {
          const int row = row0 + mb * 32 + g * 8 + j;
          out[(size_t)row * NT + n] =
              (float)acc[mb][nb][g * 4 + j] * (sxq[g][j] * sc) + bs;
        }
    }
  }
}

// ---------- fallback (raw inputs, fused bf16 convert; round-1 structure) ----------
__global__ __launch_bounds__(256) void gemm_fallback(
    const float* __restrict__ Ap, const int* __restrict__ Bp,
    const float* __restrict__ scale, const float* __restrict__ bias,
    float* __restrict__ out) {
  __shared__ short ldsA[128 * 64];
  __shared__ short ldsB[128 * 64];
  const int tid = threadIdx.x;
  const int lane = tid & 63;
  const int wid = tid >> 6;
  const int nbn = NT / 128;
  const int cpx = ((MT / 128) * nbn) / 8;
  const int bid = blockIdx.x;
  const int wg = (bid & 7) * cpx + (bid >> 3);
  const int brow = (wg / nbn) * 128;
  const int bcol = (wg % nbn) * 128;
  const int wr = wid >> 1, wc = wid & 1;
  f32x4 acc[4][4] = {{{0.f, 0.f, 0.f, 0.f}}};
  const int srow = tid >> 3;
  const int sk8 = (tid & 7) * 8;
  for (int k0 = 0; k0 < KT; k0 += 64) {
    __syncthreads();
#pragma unroll
    for (int p = 0; p < 4; p++) {
      const int row = p * 32 + srow;
      const float* s = Ap + (size_t)(brow + row) * KT + k0 + sk8;
      f32x4 lo = *(const f32x4*)s;
      f32x4 hi = *(const f32x4*)(s + 4);
      short8 v;
#pragma unroll
      for (int j = 0; j < 4; j++) { v[j] = f2bf(lo[j]); v[4 + j] = f2bf(hi[j]); }
      int bo = (row * 64 + sk8) * 2;
      bo ^= ((row & 7) << 4);
      *(short8*)((char*)ldsA + bo) = v;
    }
#pragma unroll
    for (int p = 0; p < 4; p++) {
      const int row = p * 32 + srow;
      const int* s = Bp + (size_t)(bcol + row) * KT + k0 + sk8;
      i32x4 lo = *(const i32x4*)s;
      i32x4 hi = *(const i32x4*)(s + 4);
      short8 v;
#pragma unroll
      for (int j = 0; j < 4; j++) { v[j] = f2bf((float)lo[j]); v[4 + j] = f2bf((float)hi[j]); }
      int bo = (row * 64 + sk8) * 2;
      bo ^= ((row & 7) << 4);
      *(short8*)((char*)ldsB + bo) = v;
    }
    __syncthreads();
#pragma unroll
    for (int kk = 0; kk < 2; kk++) {
      short8 af[4], bf2[4];
#pragma unroll
      for (int mi = 0; mi < 4; mi++) {
        const int row = wr * 64 + mi * 16 + (lane & 15);
        int bo = (row * 64 + kk * 32 + (lane >> 4) * 8) * 2;
        bo ^= ((row & 7) << 4);
        af[mi] = *(const short8*)((const char*)ldsA + bo);
      }
#pragma unroll
      for (int ni = 0; ni < 4; ni++) {
        const int row = wc * 64 + ni * 16 + (lane & 15);
        int bo = (row * 64 + kk * 32 + (lane >> 4) * 8) * 2;
        bo ^= ((row & 7) << 4);
        bf2[ni] = *(const short8*)((const char*)ldsB + bo);
      }
#pragma unroll
      for (int mi = 0; mi < 4; mi++)
#pragma unroll
        for (int ni = 0; ni < 4; ni++)
          acc[mi][ni] = __builtin_amdgcn_mfma_f32_16x16x32_bf16(af[mi], bf2[ni],
                                                                acc[mi][ni], 0, 0, 0);
    }
  }
#pragma unroll
  for (int ni = 0; ni < 4; ni++) {
    const int n = bcol + wc * 64 + ni * 16 + (lane & 15);
    const float sc = scale[n];
    const float bs = bias[n];
#pragma unroll
    for (int mi = 0; mi < 4; mi++) {
      const int m0 = brow + wr * 64 + mi * 16 + ((lane >> 4) << 2);
#pragma unroll
      for (int j = 0; j < 4; j++)
        out[(size_t)(m0 + j) * NT + n] = acc[mi][ni][j] * sc + bs;
    }
  }
}

extern "C" void kernel_launch(void* const* d_in, const int* in_sizes, int n_in,
                              void* d_out, int out_size, void* d_ws, size_t ws_size,
                              hipStream_t stream) {
  const float* x = (const float*)d_in[0];
  const int* w = (const int*)d_in[1];
  const float* scale = (const float*)d_in[2];
  const float* bias = (const float*)d_in[3];
  float* out = (float*)d_out;

  const size_t a_bytes = (size_t)MTILES * NKT * CHUNK_BYTES;  // 32 MB
  const size_t b_bytes = (size_t)NTILES * NKT * CHUNK_BYTES;  // 43 MB
  const size_t s_bytes = (size_t)MT * sizeof(float);          // 32 KB

  if (ws_size >= a_bytes + b_bytes + s_bytes) {
    char* aw = (char*)d_ws;
    char* bw = aw + a_bytes;
    float* sx = (float*)(bw + b_bytes);
    quant_x_kernel<<<dim3(MT), dim3(256), 0, stream>>>(x, aw, sx);
    cvt_w8_kernel<<<dim3(NT), dim3(256), 0, stream>>>(w, bw);
    hipFuncSetAttribute((const void*)gemm256,
                        hipFuncAttributeMaxDynamicSharedMemorySize, 131072);
    gemm256<<<dim3(MTILES * NTILES), dim3(512), 131072, stream>>>(
        aw, bw, sx, scale, bias, out);
  } else {
    gemm_fallback<<<dim3((MT / 128) * (NT / 128)), dim3(256), 0, stream>>>(
        x, w, scale, bias, out);
  }
}